// Round 6
// baseline (844.647 us; speedup 1.0000x reference)
//
#include <hip/hip_runtime.h>
#include <hip/hip_bf16.h>
#include <math.h>

// LocalUniFormerBlock: BN -> windowed MHSA -> +res -> LN -> MLP(gelu) -> +res
// B=4 C=128 T=16 H=56 W=56, windows 4x7x7 (N=196), NH=4 HD=32, HID=512
//
// Round-12: k12+k3 fused into k123 (1 block = window*head): BN'd A-frags
// loaded direct from x into regs (no sXn), K/V GEMM'd into LDS, Q via the
// per-wave sP lockstep transpose into regs, then the k3 attention body.
// Q/K/V global buffers eliminated -> per-batch ws footprint 205.5->51.4 MB
// -> NB shrinks (16->4 under small-ws hypothesis), 50->10 launches/rep.
// k0/k4/k5 byte-identical to round-11 passing version.

typedef __hip_bfloat16 bf16;
typedef __attribute__((ext_vector_type(8))) short short8;
typedef __attribute__((ext_vector_type(4))) short bhalf4;
typedef __attribute__((ext_vector_type(4))) float f32x4;

__device__ __forceinline__ float b2f(bf16 v) { return __bfloat162float(v); }
__device__ __forceinline__ bf16  f2b(float v) { return __float2bfloat16(v); }

// exact-GELU via Abramowitz-Stegun 7.1.26 erfc approx (|eps|<=1.5e-7), branchless
__device__ __forceinline__ float gelu_f(float v) {
    float u = v * 0.70710678118654752f;
    float a = fabsf(u);
    float t = __builtin_amdgcn_rcpf(fmaf(0.3275911f, a, 1.0f));
    float poly = t * fmaf(t, fmaf(t, fmaf(t, fmaf(t, 1.061405429f, -1.453152027f),
                                          1.421413741f), -0.284496736f), 0.254829592f);
    float E = poly * __expf(-a * a);          // = erfc(a)
    float w = (u >= 0.f) ? (2.0f - E) : E;    // = 1 + erf(u)
    return 0.5f * v * w;
}

// ---------------------------------------------------------------- K0: weight prep (bf16, [n][k] layouts)
__global__ __launch_bounds__(256) void k0_prep(
    const float* __restrict__ qkv_w, const float* __restrict__ proj_w,
    const float* __restrict__ w1, const float* __restrict__ w2,
    bf16* __restrict__ qkv_wt, bf16* __restrict__ proj_wt,
    bf16* __restrict__ w1t, bf16* __restrict__ w2t)
{
    int stride = gridDim.x * 256;
    int t0 = blockIdx.x * 256 + threadIdx.x;
    for (int i = t0; i < 384 * 128; i += stride) {       // qkv_wt[j][c] = qkv_w[c][j]
        int j = i >> 7, c = i & 127;
        qkv_wt[i] = f2b(qkv_w[c * 384 + j]);
    }
    for (int i = t0; i < 128 * 128; i += stride) {       // proj_wt[j][c] = proj_w[c][j]
        int j = i >> 7, c = i & 127;
        proj_wt[i] = f2b(proj_w[c * 128 + j]);
    }
    for (int i = t0; i < 512 * 128; i += stride) {       // w1t[j][c] = w1[c][j]
        int j = i >> 7, c = i & 127;
        w1t[i] = f2b(w1[c * 512 + j]);
    }
    for (int i = t0; i < 128 * 512; i += stride) {       // w2t[c][j] = w2[j][c]
        int c = i >> 9, j = i & 511;
        w2t[i] = f2b(w2[j * 128 + c]);
    }
}

// ---------------------------------------------------------------- K123: BN + QKV + attention (1 block = window*4 + head)
// Phase 1 (per wave, barrier-free): for its 16-row tiles mt=w+4*ti, load BN'd
// A-frags direct from x; GEMM K,V tiles (B-frags direct from L2-hot qkv_wt)
// into sK/sVt; GEMM Q tile, transpose via per-wave sP (lockstep), hold in regs.
// Phase 2 (after one barrier): k3's attention body verbatim.
__global__ __launch_bounds__(256, 3) void k123_attn(
    const float* __restrict__ x, const float* __restrict__ gamma, const float* __restrict__ beta,
    const float* __restrict__ mean, const float* __restrict__ var,
    const bf16* __restrict__ qkv_wt, const float* __restrict__ qkv_b,
    bf16* __restrict__ attn_out, int bw0)
{
    __shared__ __align__(16) bf16 sK[224][40];    // [k row][d]; rows 196..207 = bias (masked), 208..223 zero
    __shared__ __align__(16) bf16 sVt[32][232];   // [d][j]; j 196..207 = bias (masked by P=0), 208..231 zero
    __shared__ __align__(16) bf16 sP[4][16][36];  // per-wave scratch: Q transpose, then P chunks
    __shared__ float sAc[128], sBc[128];
    int bh = blockIdx.x;             // batch-local bw*4 + h
    int bw = bh >> 2; int h = bh & 3;
    int gbw = bw0 + bw;              // global window id
    int b   = gbw >> 8;
    int wid = gbw & 255;
    int t0 = (wid >> 6) * 4;
    int h0 = ((wid >> 3) & 7) * 7;
    int w0 = (wid & 7) * 7;
    int tid = threadIdx.x;
    short8 z8 = {0, 0, 0, 0, 0, 0, 0, 0};
    if (tid < 128) {
        float a = gamma[tid] * rsqrtf(var[tid] + 1e-5f);
        sAc[tid] = a;
        sBc[tid] = beta[tid] - mean[tid] * a;
    }
    for (int idx = tid; idx < 80; idx += 256) {       // sK rows 208..223 zero (5 b128/row)
        int r = 208 + idx / 5; int c8 = (idx % 5) * 8;
        *(short8*)&sK[r][c8] = z8;
    }
    for (int idx = tid; idx < 768; idx += 256) {      // sVt cols 208..231 zero
        int d = idx / 24; int j = 208 + (idx % 24);
        sVt[d][j] = f2b(0.f);
    }
    __syncthreads();

    int w = tid >> 6, lane = tid & 63;
    int quad = lane >> 4, l16 = lane & 15;
    const float* xb = x + (long)b * 128 * 50176;      // [c][thw]
    const f32x4 zero4 = {0.f, 0.f, 0.f, 0.f};
    int baseq = h * 32, basek = 128 + h * 32, basev = 256 + h * 32;
    float bq0 = qkv_b[baseq + l16],  bq1 = qkv_b[baseq + 16 + l16];
    float bk0 = qkv_b[basek + l16],  bk1 = qkv_b[basek + 16 + l16];
    float bv0 = qkv_b[basev + l16],  bv1 = qkv_b[basev + 16 + l16];

    short8 qfr[4];                    // statically indexed (4x unroll, mt<13 predicated)
    #pragma unroll
    for (int ti = 0; ti < 4; ++ti) {
        int mt = w + ti * 4;
        if (mt < 13) {
            int n = mt * 16 + l16;
            bool av = n < 196;
            int nn = av ? n : 0;
            int wt = nn / 49; int rem = nn - wt * 49;
            int wh = rem / 7; int ww = rem - wh * 7;
            long thw = ((long)(t0 + wt) * 56 + (h0 + wh)) * 56 + (w0 + ww);
            short8 af[4];
            #pragma unroll
            for (int kk = 0; kk < 4; ++kk) {
                #pragma unroll
                for (int k = 0; k < 8; ++k) {
                    int c = kk * 32 + quad * 8 + k;
                    float v = xb[(long)c * 50176 + thw];
                    bf16 bvv = f2b(v * sAc[c] + sBc[c]);
                    af[kk][k] = av ? *(short*)&bvv : (short)0;
                }
            }
            f32x4 c0, c1;
            // ---- K tile ----
            c0 = zero4; c1 = zero4;
            #pragma unroll
            for (int kk = 0; kk < 4; ++kk) {
                short8 wb0 = *(const short8*)&qkv_wt[(long)(basek + l16) * 128 + kk * 32 + quad * 8];
                short8 wb1 = *(const short8*)&qkv_wt[(long)(basek + 16 + l16) * 128 + kk * 32 + quad * 8];
                c0 = __builtin_amdgcn_mfma_f32_16x16x32_bf16(af[kk], wb0, c0, 0, 0, 0);
                c1 = __builtin_amdgcn_mfma_f32_16x16x32_bf16(af[kk], wb1, c1, 0, 0, 0);
            }
            #pragma unroll
            for (int r = 0; r < 4; ++r) {
                int row = mt * 16 + quad * 4 + r;
                sK[row][l16]      = f2b(c0[r] + bk0);
                sK[row][16 + l16] = f2b(c1[r] + bk1);
            }
            // ---- V tile (transposed store) ----
            c0 = zero4; c1 = zero4;
            #pragma unroll
            for (int kk = 0; kk < 4; ++kk) {
                short8 wb0 = *(const short8*)&qkv_wt[(long)(basev + l16) * 128 + kk * 32 + quad * 8];
                short8 wb1 = *(const short8*)&qkv_wt[(long)(basev + 16 + l16) * 128 + kk * 32 + quad * 8];
                c0 = __builtin_amdgcn_mfma_f32_16x16x32_bf16(af[kk], wb0, c0, 0, 0, 0);
                c1 = __builtin_amdgcn_mfma_f32_16x16x32_bf16(af[kk], wb1, c1, 0, 0, 0);
            }
            #pragma unroll
            for (int r = 0; r < 4; ++r) {
                int j = mt * 16 + quad * 4 + r;
                sVt[l16][j]      = f2b(c0[r] + bv0);
                sVt[16 + l16][j] = f2b(c1[r] + bv1);
            }
            // ---- Q tile -> per-wave sP transpose -> regs (same-wave lockstep) ----
            c0 = zero4; c1 = zero4;
            #pragma unroll
            for (int kk = 0; kk < 4; ++kk) {
                short8 wb0 = *(const short8*)&qkv_wt[(long)(baseq + l16) * 128 + kk * 32 + quad * 8];
                short8 wb1 = *(const short8*)&qkv_wt[(long)(baseq + 16 + l16) * 128 + kk * 32 + quad * 8];
                c0 = __builtin_amdgcn_mfma_f32_16x16x32_bf16(af[kk], wb0, c0, 0, 0, 0);
                c1 = __builtin_amdgcn_mfma_f32_16x16x32_bf16(af[kk], wb1, c1, 0, 0, 0);
            }
            #pragma unroll
            for (int r = 0; r < 4; ++r) {
                sP[w][quad * 4 + r][l16]      = f2b(c0[r] + bq0);
                sP[w][quad * 4 + r][16 + l16] = f2b(c1[r] + bq1);
            }
            bhalf4 qlo = *(const bhalf4*)&sP[w][l16][quad * 8];
            bhalf4 qhi = *(const bhalf4*)&sP[w][l16][quad * 8 + 4];
            qfr[ti] = (short8){qlo[0], qlo[1], qlo[2], qlo[3], qhi[0], qhi[1], qhi[2], qhi[3]};
        }
    }
    __syncthreads();

    // ---- attention: k3 body verbatim (qf pre-held in regs) ----
    const float scale = 0.17677669529663687f;
    #pragma unroll
    for (int ti = 0; ti < 4; ++ti) {
        int mt = w + ti * 4;
        if (mt < 13) {
            short8 qf = qfr[ti];
            f32x4 oacc0 = zero4, oacc1 = zero4;
            float lsum[4] = {0.f, 0.f, 0.f, 0.f};
            for (int cc = 0; cc < 7; ++cc) {
                #pragma unroll
                for (int t2 = 0; t2 < 2; ++t2) {
                    int col0 = cc * 32 + t2 * 16;
                    short8 kf = *(const short8*)&sK[col0 + l16][quad * 8];
                    f32x4 s = __builtin_amdgcn_mfma_f32_16x16x32_bf16(qf, kf, zero4, 0, 0, 0);
                    bool valid = (col0 + l16) < 196;
                    #pragma unroll
                    for (int r = 0; r < 4; ++r) {
                        float p = valid ? __expf(s[r] * scale) : 0.f;
                        lsum[r] += p;
                        sP[w][quad * 4 + r][t2 * 16 + l16] = f2b(p);
                    }
                }
                bhalf4 plo = *(const bhalf4*)&sP[w][l16][quad * 8];
                bhalf4 phi = *(const bhalf4*)&sP[w][l16][quad * 8 + 4];
                short8 pf = {plo[0], plo[1], plo[2], plo[3], phi[0], phi[1], phi[2], phi[3]};
                short8 vf0 = *(const short8*)&sVt[l16][cc * 32 + quad * 8];
                short8 vf1 = *(const short8*)&sVt[16 + l16][cc * 32 + quad * 8];
                oacc0 = __builtin_amdgcn_mfma_f32_16x16x32_bf16(pf, vf0, oacc0, 0, 0, 0);
                oacc1 = __builtin_amdgcn_mfma_f32_16x16x32_bf16(pf, vf1, oacc1, 0, 0, 0);
            }
            #pragma unroll
            for (int off = 1; off < 16; off <<= 1) {
                #pragma unroll
                for (int r = 0; r < 4; ++r) lsum[r] += __shfl_xor(lsum[r], off, 64);
            }
            #pragma unroll
            for (int r = 0; r < 4; ++r) {
                int row = mt * 16 + quad * 4 + r;
                if (row < 196) {
                    float inv = 1.0f / lsum[r];
                    bf16* op = attn_out + ((long)(bw * 196) + row) * 128 + h * 32;
                    op[l16]      = f2b(oacc0[r] * inv);
                    op[16 + l16] = f2b(oacc1[r] * inv);
                }
            }
        }
    }
}

// ---------------------------------------------------------------- K4: proj GEMM via MFMA + residual -> d_out (ch-major, fp32)
__global__ __launch_bounds__(256) void k4_proj(
    const bf16* __restrict__ attn, const bf16* __restrict__ proj_wt, const float* __restrict__ proj_b,
    const float* __restrict__ x, float* __restrict__ y, int bw0)
{
    __shared__ __align__(16) bf16 sA[64][136];   // [token][c]
    __shared__ __align__(16) bf16 sB[64][136];   // [out j][c]
    __shared__ float sC[64][69];                 // [token][j]
    int t0 = blockIdx.x * 64;        // batch-local token
    int j0 = blockIdx.y * 64;
    int tid = threadIdx.x;
    for (int idx = tid; idx < 64 * 16; idx += 256) {
        int i = idx >> 4; int c8 = (idx & 15) * 8;
        *(short8*)&sA[i][c8] = *(const short8*)&attn[(long)(t0 + i) * 128 + c8];
    }
    for (int idx = tid; idx < 64 * 16; idx += 256) {
        int j = idx >> 4; int c8 = (idx & 15) * 8;
        *(short8*)&sB[j][c8] = *(const short8*)&proj_wt[(long)(j0 + j) * 128 + c8];
    }
    __syncthreads();
    int w = tid >> 6, lane = tid & 63;
    int quad = lane >> 4, l16 = lane & 15;
    int w16 = w * 16;
    f32x4 acc[4];
    #pragma unroll
    for (int nt = 0; nt < 4; ++nt) acc[nt] = (f32x4){0.f, 0.f, 0.f, 0.f};
    #pragma unroll
    for (int kk = 0; kk < 4; ++kk) {
        short8 af = *(const short8*)&sA[w16 + l16][kk * 32 + quad * 8];
        #pragma unroll
        for (int nt = 0; nt < 4; ++nt) {
            short8 bfq = *(const short8*)&sB[nt * 16 + l16][kk * 32 + quad * 8];
            acc[nt] = __builtin_amdgcn_mfma_f32_16x16x32_bf16(af, bfq, acc[nt], 0, 0, 0);
        }
    }
    #pragma unroll
    for (int nt = 0; nt < 4; ++nt) {
        int n = nt * 16 + l16;
        float bias = proj_b[j0 + n];
        #pragma unroll
        for (int r = 0; r < 4; ++r) {
            sC[w16 + quad * 4 + r][n] = acc[nt][r] + bias;
        }
    }
    __syncthreads();
    for (int idx = tid; idx < 4096; idx += 256) {     // lanes sweep token -> 28B-contiguous x/y runs
        int j = idx >> 6; int tl = idx & 63;
        int gj = j0 + j;
        int tk = t0 + tl;
        int lbw = tk / 196; int n = tk - lbw * 196;
        int gbw = bw0 + lbw;                           // global window id
        int b = gbw >> 8; int wid = gbw & 255;
        int wt = n / 49; int rem = n - wt * 49;
        int tt = (wid >> 6) * 4 + wt;
        int hh = ((wid >> 3) & 7) * 7 + rem / 7;
        int wcol = (wid & 7) * 7 + (rem - (rem / 7) * 7);
        int thw = (tt * 56 + hh) * 56 + wcol;
        long off = (long)(b * 128 + gj) * 50176 + thw;
        y[off] = sC[tl][j] + x[off];                   // channel-major fp32, same layout as out
    }
}

// ---------------------------------------------------------------- K5: LN + MLP (MFMA) + residual, IN-PLACE on d_out
// v3: A-frags in regs, short-lived res, async weight staging, LDS=23552.
__global__ __launch_bounds__(256, 4) void k5_mlp(
    float* __restrict__ y,           // in: x+attn residual (ch-major); out: final (ch-major)
    const float* __restrict__ ln_g, const float* __restrict__ ln_b,
    const bf16* __restrict__ w1t, const float* __restrict__ b1,
    const bf16* __restrict__ w2t, const float* __restrict__ b2)
{
    // Region R (18944 B): phase1 = LN transpose [64][136]; ch-loop = sW1[32][136]+sW2[128][40];
    // epilogue = sOut [64][136]. sH (4608 B): stats in prologue, gelu(fc1) chunk in ch-loop.
    __shared__ __align__(16) unsigned char Rraw[18944];
    __shared__ __align__(16) bf16 sH[64][36];
    bf16 (*lnT)[136] = (bf16(*)[136])Rraw;
    bf16 (*sW1)[136] = (bf16(*)[136])Rraw;                 // [32][136]
    bf16 (*sW2)[40]  = (bf16(*)[40])(Rraw + 32 * 136 * 2); // [128][40]
    float* sPa   = (float*)&sH[0][0];   // [4][64]
    float* sPb   = sPa + 256;           // [4][64]
    float* sMu   = sPb + 256;           // [64]
    float* sRstd = sMu + 64;            // [64]   (2560 B <= 4608)

    int tid = threadIdx.x;
    int g0 = blockIdx.x * 64;        // 50176%64==0 so one b per block
    int b = g0 / 50176;
    int thw0 = g0 - b * 50176;
    int tok = tid & 63;
    int cg = tid >> 6;               // 0..3 -> this thread's 32-channel group
    int c0 = cg * 32;
    float* yb = y + (long)(b * 128 + c0) * 50176 + thw0 + tok;

    // prologue: stats + LN; res[] dies before the ch-loop (no long live range)
    {
        float res[32];
        float s = 0.f, s2 = 0.f;
        #pragma unroll
        for (int k = 0; k < 32; ++k) {
            float v = yb[(long)k * 50176];
            res[k] = v; s += v; s2 += v * v;
        }
        sPa[cg * 64 + tok] = s; sPb[cg * 64 + tok] = s2;
        __syncthreads();
        if (tid < 64) {
            float ss  = sPa[tid] + sPa[64 + tid] + sPa[128 + tid] + sPa[192 + tid];
            float ss2 = sPb[tid] + sPb[64 + tid] + sPb[128 + tid] + sPb[192 + tid];
            float mu = ss * (1.0f / 128.0f);
            float var = ss2 * (1.0f / 128.0f) - mu * mu;
            sMu[tid] = mu;
            sRstd[tid] = rsqrtf(fmaxf(var, 0.f) + 1e-5f);
        }
        __syncthreads();
        float mu = sMu[tok], rstd = sRstd[tok];
        #pragma unroll
        for (int k8 = 0; k8 < 4; ++k8) {
            short8 pk;
            #pragma unroll
            for (int k = 0; k < 8; ++k) {
                int c = c0 + k8 * 8 + k;
                bf16 hv = f2b((res[k8 * 8 + k] - mu) * rstd * ln_g[c] + ln_b[c]);
                pk[k] = *(short*)&hv;
            }
            *(short8*)&lnT[tok][c0 + k8 * 8] = pk;
        }
    }
    __syncthreads();

    int w = tid >> 6, lane = tid & 63;
    int quad = lane >> 4, l16 = lane & 15;
    int w16 = w * 16;
    // A-fragments for this wave's 16 tokens into registers (16 VGPRs)
    short8 afr[4];
    #pragma unroll
    for (int kk = 0; kk < 4; ++kk)
        afr[kk] = *(const short8*)&lnT[w16 + l16][kk * 32 + quad * 8];
    __syncthreads();   // lnT reads done -> region becomes weight buffers

    // staging indices (fixed per thread)
    int j0i = tid >> 4, c8a = (tid & 15) * 8;   // W1: rows j0i and j0i+16
    int ca  = tid >> 2, j8a = (tid & 3) * 8;    // W2: rows ca and ca+64
    short8 r1a, r1b, r2a, r2b;
    r1a = *(const short8*)&w1t[(long)(0 * 32 + j0i) * 128 + c8a];
    r1b = *(const short8*)&w1t[(long)(0 * 32 + j0i + 16) * 128 + c8a];
    r2a = *(const short8*)&w2t[(long)ca * 512 + 0 * 32 + j8a];
    r2b = *(const short8*)&w2t[(long)(ca + 64) * 512 + 0 * 32 + j8a];
    *(short8*)&sW1[j0i][c8a]      = r1a;
    *(short8*)&sW1[j0i + 16][c8a] = r1b;
    *(short8*)&sW2[ca][j8a]       = r2a;
    *(short8*)&sW2[ca + 64][j8a]  = r2b;
    __syncthreads();

    f32x4 facc[8];
    #pragma unroll
    for (int t = 0; t < 8; ++t) facc[t] = (f32x4){0.f, 0.f, 0.f, 0.f};

    for (int ch = 0; ch < 16; ++ch) {
        if (ch < 15) {   // issue next chunk's loads; latency hides under fc1/fc2
            r1a = *(const short8*)&w1t[(long)((ch + 1) * 32 + j0i) * 128 + c8a];
            r1b = *(const short8*)&w1t[(long)((ch + 1) * 32 + j0i + 16) * 128 + c8a];
            r2a = *(const short8*)&w2t[(long)ca * 512 + (ch + 1) * 32 + j8a];
            r2b = *(const short8*)&w2t[(long)(ca + 64) * 512 + (ch + 1) * 32 + j8a];
        }
        #pragma unroll
        for (int t = 0; t < 2; ++t) {
            f32x4 a = (f32x4){0.f, 0.f, 0.f, 0.f};
            #pragma unroll
            for (int kk = 0; kk < 4; ++kk) {
                short8 bfq = *(const short8*)&sW1[t * 16 + l16][kk * 32 + quad * 8];
                a = __builtin_amdgcn_mfma_f32_16x16x32_bf16(afr[kk], bfq, a, 0, 0, 0);
            }
            float bias = b1[ch * 32 + t * 16 + l16];
            #pragma unroll
            for (int r = 0; r < 4; ++r) {
                sH[w16 + quad * 4 + r][t * 16 + l16] = f2b(gelu_f(a[r] + bias));
            }
        }
        // fc1 writes / fc2 reads of sH touch only rows [w16,w16+16): same-wave, lgkm-ordered
        bhalf4 h0 = *(const bhalf4*)&sH[w16 + l16][quad * 8];
        bhalf4 h1 = *(const bhalf4*)&sH[w16 + l16][quad * 8 + 4];
        short8 hf = {h0[0], h0[1], h0[2], h0[3], h1[0], h1[1], h1[2], h1[3]};
        #pragma unroll
        for (int t = 0; t < 8; ++t) {
            short8 wf = *(const short8*)&sW2[t * 16 + l16][quad * 8];
            facc[t] = __builtin_amdgcn_mfma_f32_16x16x32_bf16(hf, wf, facc[t], 0, 0, 0);
        }
        if (ch < 15) {
            __syncthreads();               // all readers done with current weights
            *(short8*)&sW1[j0i][c8a]      = r1a;
            *(short8*)&sW1[j0i + 16][c8a] = r1b;
            *(short8*)&sW2[ca][j8a]       = r2a;
            *(short8*)&sW2[ca + 64][j8a]  = r2b;
            __syncthreads();               // new weights visible
        }
    }
    __syncthreads();   // last fc2 reads done -> region becomes sOut
    bf16 (*sOut)[136] = lnT;
    #pragma unroll
    for (int t = 0; t < 8; ++t) {
        int c = t * 16 + l16;
        float b2v = b2[c];
        #pragma unroll
        for (int r = 0; r < 4; ++r) {
            sOut[w16 + quad * 4 + r][c] = f2b(facc[t][r] + b2v);
        }
    }
    __syncthreads();
    #pragma unroll
    for (int k8 = 0; k8 < 4; ++k8) {
        short8 ov = *(const short8*)&sOut[tok][c0 + k8 * 8];
        #pragma unroll
        for (int k = 0; k < 8; ++k) {
            short sv = ov[k];
            bf16 bv = *(bf16*)&sv;
            long off = (long)(k8 * 8 + k) * 50176;
            yb[off] = yb[off] + b2f(bv);   // residual re-read (L2-warm), add, store
        }
    }
}

// ----------------------------------------------------------------
extern "C" void kernel_launch(void* const* d_in, const int* in_sizes, int n_in,
                              void* d_out, int out_size, void* d_ws, size_t ws_size,
                              hipStream_t stream) {
    const float* x      = (const float*)d_in[0];
    const float* bn_g   = (const float*)d_in[1];
    const float* bn_b   = (const float*)d_in[2];
    const float* bn_m   = (const float*)d_in[3];
    const float* bn_v   = (const float*)d_in[4];
    const float* qkv_w  = (const float*)d_in[5];
    const float* qkv_b  = (const float*)d_in[6];
    const float* proj_w = (const float*)d_in[7];
    const float* proj_b = (const float*)d_in[8];
    const float* ln_g   = (const float*)d_in[9];
    const float* ln_b   = (const float*)d_in[10];
    const float* fc1_w  = (const float*)d_in[11];
    const float* fc1_b  = (const float*)d_in[12];
    const float* fc2_w  = (const float*)d_in[13];
    const float* fc2_b  = (const float*)d_in[14];
    float* out = (float*)d_out;

    // weight prep region at front of ws: qkv_wt(98304B) proj_wt(32768B) w1t(131072B) w2t(131072B)
    const size_t WB = 393216;
    char* ws = (char*)d_ws;
    bf16* qkv_wt  = (bf16*)ws;
    bf16* proj_wt = qkv_wt + 384 * 128;
    bf16* w1t     = proj_wt + 128 * 128;
    bf16* w2t     = w1t + 512 * 128;
    char* ws2 = ws + WB;

    // per-batch ws footprint is now ONLY the attn buffer (WPB*196*128*2 B)
    int NB = 1;
    while (NB < 64 && (51380224ull / NB + WB) > ws_size) NB *= 2;
    int WPB = 1024 / NB;             // windows per batch
    int TPB = WPB * 196;             // tokens per batch

    bf16* attn = (bf16*)(ws2);       // attn staging (k123 -> k4)

    k0_prep<<<dim3(192), dim3(256), 0, stream>>>(qkv_w, proj_w, fc1_w, fc2_w,
                                                 qkv_wt, proj_wt, w1t, w2t);
    for (int bi = 0; bi < NB; ++bi) {
        int bw0 = bi * WPB;
        k123_attn<<<dim3(WPB * 4), dim3(256), 0, stream>>>(x, bn_g, bn_b, bn_m, bn_v,
                                                           qkv_wt, qkv_b, attn, bw0);
        k4_proj<<<dim3(TPB / 64, 2), dim3(256), 0, stream>>>(attn, proj_wt, proj_b, x, out, bw0);
    }
    k5_mlp<<<dim3(3136), dim3(256), 0, stream>>>(out, ln_g, ln_b, w1t, fc1_b, w2t, fc2_b);
}

// Round 8
// 564.873 us; speedup vs baseline: 1.4953x; 1.4953x over previous
//
#include <hip/hip_runtime.h>
#include <hip/hip_bf16.h>
#include <math.h>

// LocalUniFormerBlock: BN -> windowed MHSA -> +res -> LN -> MLP(gelu) -> +res
// B=4 C=128 T=16 H=56 W=56, windows 4x7x7 (N=196), NH=4 HD=32, HID=512
//
// Round-14 == Round-13 resubmit (bench died to container infra failure with
// no pytest output; source re-audited for compile/alias/index/resource
// defects, none found — byte-identical resubmit per round-9 precedent).
// Round-13: revert k123 (4x redundant x gather, FETCH=480MB) -> round-11
// k12+k3. NEW: k4+k5 fused into k45 (per 64-token thw chunk): attn gather
// via inverse window map, proj GEMM in-block, x residual into regs, then
// k5-v3's LN+MLP verbatim, single final y write. Eliminates the y=x+attn
// global round-trip (~360 MB). LDS pool 52480 B -> 3 blocks/CU.
// k0/k12/k3 byte-identical to round-11 passing version.

typedef __hip_bfloat16 bf16;
typedef __attribute__((ext_vector_type(8))) short short8;
typedef __attribute__((ext_vector_type(4))) short bhalf4;
typedef __attribute__((ext_vector_type(4))) float f32x4;

__device__ __forceinline__ float b2f(bf16 v) { return __bfloat162float(v); }
__device__ __forceinline__ bf16  f2b(float v) { return __float2bfloat16(v); }

// exact-GELU via Abramowitz-Stegun 7.1.26 erfc approx (|eps|<=1.5e-7), branchless
__device__ __forceinline__ float gelu_f(float v) {
    float u = v * 0.70710678118654752f;
    float a = fabsf(u);
    float t = __builtin_amdgcn_rcpf(fmaf(0.3275911f, a, 1.0f));
    float poly = t * fmaf(t, fmaf(t, fmaf(t, fmaf(t, 1.061405429f, -1.453152027f),
                                          1.421413741f), -0.284496736f), 0.254829592f);
    float E = poly * __expf(-a * a);          // = erfc(a)
    float w = (u >= 0.f) ? (2.0f - E) : E;    // = 1 + erf(u)
    return 0.5f * v * w;
}

// ---------------------------------------------------------------- K0: weight prep (bf16, [n][k] layouts)
__global__ __launch_bounds__(256) void k0_prep(
    const float* __restrict__ qkv_w, const float* __restrict__ proj_w,
    const float* __restrict__ w1, const float* __restrict__ w2,
    bf16* __restrict__ qkv_wt, bf16* __restrict__ proj_wt,
    bf16* __restrict__ w1t, bf16* __restrict__ w2t)
{
    int stride = gridDim.x * 256;
    int t0 = blockIdx.x * 256 + threadIdx.x;
    for (int i = t0; i < 384 * 128; i += stride) {       // qkv_wt[j][c] = qkv_w[c][j]
        int j = i >> 7, c = i & 127;
        qkv_wt[i] = f2b(qkv_w[c * 384 + j]);
    }
    for (int i = t0; i < 128 * 128; i += stride) {       // proj_wt[j][c] = proj_w[c][j]
        int j = i >> 7, c = i & 127;
        proj_wt[i] = f2b(proj_w[c * 128 + j]);
    }
    for (int i = t0; i < 512 * 128; i += stride) {       // w1t[j][c] = w1[c][j]
        int j = i >> 7, c = i & 127;
        w1t[i] = f2b(w1[c * 512 + j]);
    }
    for (int i = t0; i < 128 * 512; i += stride) {       // w2t[c][j] = w2[j][c]
        int c = i >> 9, j = i & 511;
        w2t[i] = f2b(w2[j * 128 + c]);
    }
}

// ---------------------------------------------------------------- K12: BN + window partition + QKV GEMM (1 block = 1 window)
__global__ __launch_bounds__(256) void k12_bn_qkv(
    const float* __restrict__ x, const float* __restrict__ gamma, const float* __restrict__ beta,
    const float* __restrict__ mean, const float* __restrict__ var,
    const bf16* __restrict__ qkv_wt, const float* __restrict__ qkv_b,
    bf16* __restrict__ Q, bf16* __restrict__ K, bf16* __restrict__ V, int bw0)
{
    __shared__ __align__(16) bf16 sXn[208][136];   // BN'd window [token][c]; rows 196..207 zero
    __shared__ __align__(16) bf16 sB[64][136];     // weight chunk [j][c]
    __shared__ float sAc[128], sBc[128];
    int lbw = blockIdx.x;            // batch-local window
    int gbw = bw0 + lbw;             // global window id
    int b   = gbw >> 8;
    int wid = gbw & 255;
    int t0 = (wid >> 6) * 4;
    int h0 = ((wid >> 3) & 7) * 7;
    int w0 = (wid & 7) * 7;
    int tid = threadIdx.x;
    if (tid < 128) {
        float a = gamma[tid] * rsqrtf(var[tid] + 1e-5f);
        sAc[tid] = a;
        sBc[tid] = beta[tid] - mean[tid] * a;
    }
    __syncthreads();
    for (int idx = tid; idx < 128 * 196; idx += 256) {   // gather + BN (28B-contiguous x runs per c)
        int c = idx / 196;
        int n = idx - c * 196;
        int wt = n / 49; int rem = n - wt * 49;
        int wh = rem / 7; int ww = rem - wh * 7;
        int gi = (((b * 128 + c) * 16 + (t0 + wt)) * 56 + (h0 + wh)) * 56 + (w0 + ww);
        sXn[n][c] = f2b(x[gi] * sAc[c] + sBc[c]);
    }
    for (int idx = tid; idx < 12 * 16; idx += 256) {     // zero pad rows 196..207
        int row = 196 + (idx >> 4); int c8 = (idx & 15) * 8;
        *(short8*)&sXn[row][c8] = (short8){0, 0, 0, 0, 0, 0, 0, 0};
    }
    int w = tid >> 6, lane = tid & 63;
    int quad = lane >> 4, l16 = lane & 15;
    const f32x4 zero4 = {0.f, 0.f, 0.f, 0.f};
    for (int jc = 0; jc < 6; ++jc) {
        __syncthreads();   // prev jc readers of sB done; (jc==0: orders sXn writes too)
        for (int idx = tid; idx < 1024; idx += 256) {    // stage 64x128 weight chunk
            int j = idx >> 4; int c8 = (idx & 15) * 8;
            *(short8*)&sB[j][c8] = *(const short8*)&qkv_wt[(long)(jc * 64 + j) * 128 + c8];
        }
        __syncthreads();
        bf16* outw = (jc < 2) ? Q : (jc < 4 ? K : V);
        int jb = (jc & 1) * 64;
        for (int mt = w; mt < 13; mt += 4) {
            f32x4 acc[4];
            #pragma unroll
            for (int nt = 0; nt < 4; ++nt) acc[nt] = zero4;
            #pragma unroll
            for (int kk = 0; kk < 4; ++kk) {
                short8 af = *(const short8*)&sXn[mt * 16 + l16][kk * 32 + quad * 8];
                #pragma unroll
                for (int nt = 0; nt < 4; ++nt) {
                    short8 bfq = *(const short8*)&sB[nt * 16 + l16][kk * 32 + quad * 8];
                    acc[nt] = __builtin_amdgcn_mfma_f32_16x16x32_bf16(af, bfq, acc[nt], 0, 0, 0);
                }
            }
            #pragma unroll
            for (int nt = 0; nt < 4; ++nt) {
                int jcol = jb + nt * 16 + l16;           // 0..127 within Q/K/V
                int h = jcol >> 5, d = jcol & 31;
                float bias = qkv_b[jc * 64 + nt * 16 + l16];
                bf16* base = outw + ((long)(lbw * 4 + h) * 196) * 32 + d;
                #pragma unroll
                for (int r = 0; r < 4; ++r) {
                    int n = mt * 16 + quad * 4 + r;
                    if (n < 196) base[(long)n * 32] = f2b(acc[nt][r] + bias);
                }
            }
        }
    }
}

// ---------------------------------------------------------------- K3: MFMA attention per (batch-local window, head)
__global__ __launch_bounds__(256) void k3_attn(
    const bf16* __restrict__ Q, const bf16* __restrict__ K, const bf16* __restrict__ V,
    bf16* __restrict__ attn_out)
{
    __shared__ __align__(16) bf16 sQ[208][36];    // [q row][d], rows 196..207 zero (stride 36 => b64 reads)
    __shared__ __align__(16) bf16 sK[224][40];    // [k row][d], rows 196..223 zero
    __shared__ __align__(16) bf16 sVt[32][232];   // [d][j], j 196..223 zero
    __shared__ __align__(16) bf16 sP[4][16][36];  // per-wave P chunk [m][k] (stride 36 => b64 reads)
    int bh = blockIdx.x;             // batch-local bw*4 + h
    int bw = bh >> 2; int h = bh & 3;
    int tid = threadIdx.x;
    const bf16* qp = Q + (long)bh * 6272;
    const bf16* kp = K + (long)bh * 6272;
    const bf16* vp = V + (long)bh * 6272;
    short8 z8 = {0, 0, 0, 0, 0, 0, 0, 0};
    bhalf4 z4 = {0, 0, 0, 0};
    for (int idx = tid; idx < 784; idx += 256) {      // Q/K: 196 rows x 32 d, 8-wide
        int row = idx >> 2; int c8 = (idx & 3) * 8;
        short8 qv = *(const short8*)&qp[idx * 8];
        bhalf4 qlo = {qv[0], qv[1], qv[2], qv[3]};
        bhalf4 qhi = {qv[4], qv[5], qv[6], qv[7]};
        *(bhalf4*)&sQ[row][c8]     = qlo;
        *(bhalf4*)&sQ[row][c8 + 4] = qhi;
        *(short8*)&sK[row][c8] = *(const short8*)&kp[idx * 8];
    }
    for (int idx = tid; idx < 48; idx += 256) {       // Q pad rows 196..207
        int row = 196 + (idx >> 2); int c8 = (idx & 3) * 8;
        *(bhalf4*)&sQ[row][c8]     = z4;
        *(bhalf4*)&sQ[row][c8 + 4] = z4;
    }
    for (int idx = tid; idx < 112; idx += 256) {      // K pad rows 196..223
        *(short8*)&sK[196 + (idx >> 2)][(idx & 3) * 8] = z8;
    }
    for (int idx = tid; idx < 784; idx += 256) {      // V transpose: short8 loads, scalar b16 scatter
        int j = idx >> 2; int d0 = (idx & 3) * 8;
        short8 vv = *(const short8*)&vp[j * 32 + d0];
        #pragma unroll
        for (int k = 0; k < 8; ++k) *(short*)&sVt[d0 + k][j] = vv[k];
    }
    for (int idx = tid; idx < 32 * 28; idx += 256) {  // V^T pad cols 196..223
        int d = idx / 28; int j = 196 + (idx - d * 28);
        sVt[d][j] = f2b(0.f);
    }
    __syncthreads();
    int w = tid >> 6, lane = tid & 63;
    int quad = lane >> 4, l16 = lane & 15;
    const float scale = 0.17677669529663687f;
    const f32x4 zero4 = {0.f, 0.f, 0.f, 0.f};
    for (int mt = w; mt < 13; mt += 4) {
        bhalf4 qlo = *(const bhalf4*)&sQ[mt * 16 + l16][quad * 8];
        bhalf4 qhi = *(const bhalf4*)&sQ[mt * 16 + l16][quad * 8 + 4];
        short8 qf = {qlo[0], qlo[1], qlo[2], qlo[3], qhi[0], qhi[1], qhi[2], qhi[3]};
        f32x4 oacc0 = zero4, oacc1 = zero4;
        float lsum[4] = {0.f, 0.f, 0.f, 0.f};
        for (int cc = 0; cc < 7; ++cc) {
            #pragma unroll
            for (int t2 = 0; t2 < 2; ++t2) {
                int col0 = cc * 32 + t2 * 16;
                short8 kf = *(const short8*)&sK[col0 + l16][quad * 8];
                f32x4 s = __builtin_amdgcn_mfma_f32_16x16x32_bf16(qf, kf, zero4, 0, 0, 0);
                bool valid = (col0 + l16) < 196;
                #pragma unroll
                for (int r = 0; r < 4; ++r) {
                    float p = valid ? __expf(s[r] * scale) : 0.f;
                    lsum[r] += p;
                    sP[w][quad * 4 + r][t2 * 16 + l16] = f2b(p);
                }
            }
            // same-wave LDS write->read (lockstep; pattern HW-validated by old k3)
            bhalf4 plo = *(const bhalf4*)&sP[w][l16][quad * 8];
            bhalf4 phi = *(const bhalf4*)&sP[w][l16][quad * 8 + 4];
            short8 pf = {plo[0], plo[1], plo[2], plo[3], phi[0], phi[1], phi[2], phi[3]};
            short8 vf0 = *(const short8*)&sVt[l16][cc * 32 + quad * 8];
            short8 vf1 = *(const short8*)&sVt[16 + l16][cc * 32 + quad * 8];
            oacc0 = __builtin_amdgcn_mfma_f32_16x16x32_bf16(pf, vf0, oacc0, 0, 0, 0);
            oacc1 = __builtin_amdgcn_mfma_f32_16x16x32_bf16(pf, vf1, oacc1, 0, 0, 0);
        }
        #pragma unroll
        for (int off = 1; off < 16; off <<= 1) {
            #pragma unroll
            for (int r = 0; r < 4; ++r) lsum[r] += __shfl_xor(lsum[r], off, 64);
        }
        #pragma unroll
        for (int r = 0; r < 4; ++r) {
            int row = mt * 16 + quad * 4 + r;
            if (row < 196) {
                float inv = 1.0f / lsum[r];
                bf16* op = attn_out + ((long)(bw * 196) + row) * 128 + h * 32;
                op[l16]      = f2b(oacc0[r] * inv);
                op[16 + l16] = f2b(oacc1[r] * inv);
            }
        }
    }
}

// ---------------------------------------------------------------- K45: proj GEMM + residual + LN + MLP + residual, single final y write
// 1 block = 64 consecutive thw tokens of one b. attn rows gathered via the
// inverse window map; proj via k4's MFMA fragments (2 x 64-col chunks, fp32
// sCf); res[32] in regs; then k5-v3's LN+MLP ch-loop; write final y once.
// LDS pool 52480 B, aliased:
//  [0,17408)      sA[64][136]           / lnT / sOut
//  [17408,34816)  sB[64][136]           / stats(2560) / W-region head
//  [34816,52480)  sCf[64][69] f32(17664)/ W-region tail(1536) + sH@36352 + sRow@40960
__global__ __launch_bounds__(256, 3) void k45_proj_mlp(
    const bf16* __restrict__ attn, const bf16* __restrict__ proj_wt, const float* __restrict__ proj_b,
    const float* __restrict__ x, float* __restrict__ y,
    const float* __restrict__ ln_g, const float* __restrict__ ln_b,
    const bf16* __restrict__ w1t, const float* __restrict__ b1,
    const bf16* __restrict__ w2t, const float* __restrict__ b2, int bw0)
{
    __shared__ __align__(16) unsigned char pool[52480];
    bf16 (*sA)[136]  = (bf16(*)[136])pool;                    // attn rows [m][c]
    bf16 (*lnT)[136] = (bf16(*)[136])pool;
    bf16 (*sB)[136]  = (bf16(*)[136])(pool + 17408);          // proj_wt chunk [j][c]
    bf16 (*sW1)[136] = (bf16(*)[136])(pool + 17408);          // [32][136] = 8704
    bf16 (*sW2)[40]  = (bf16(*)[40]) (pool + 17408 + 8704);   // [128][40] = 10240 (ends 36352)
    float (*sCf)[69] = (float(*)[69])(pool + 34816);          // proj result fp32 [64][69]
    bf16 (*sH)[36]   = (bf16(*)[36]) (pool + 36352);          // [64][36] = 4608 (ends 40960)
    float* sPa   = (float*)(pool + 17408);                    // [4][64]
    float* sPb   = sPa + 256;
    float* sMu   = sPb + 256;
    float* sRstd = sMu + 64;                                  // ends 17408+2560
    int*   sRow  = (int*)(pool + 40960);                      // [64]

    int tid = threadIdx.x;
    long g0 = (long)bw0 * 196 + (long)blockIdx.x * 64;   // global token index
    int b = (int)(g0 / 50176);
    int thw0 = (int)(g0 - (long)b * 50176);
    int tok = tid & 63;
    int cg = tid >> 6;
    int w = cg, lane = tid & 63;
    int quad = lane >> 4, l16 = lane & 15;
    int w16 = w * 16;

    // phase 0: inverse window map for the 64 tokens
    if (tid < 64) {
        int thw = thw0 + tid;
        int t = thw / 3136; int r2 = thw - t * 3136;
        int hh = r2 / 56;   int ww = r2 - hh * 56;
        int wid = (t >> 2) * 64 + (hh / 7) * 8 + (ww / 7);
        int n = (t & 3) * 49 + (hh % 7) * 7 + (ww % 7);
        sRow[tid] = (b * 256 + wid - bw0) * 196 + n;     // batch-local attn row
    }
    __syncthreads();
    // phase 1: stage sA (attn rows, 256B contiguous each) + sB chunk 0
    for (int idx = tid; idx < 1024; idx += 256) {
        int m = idx >> 4; int c8 = (idx & 15) * 8;
        *(short8*)&sA[m][c8] = *(const short8*)&attn[(long)sRow[m] * 128 + c8];
    }
    for (int idx = tid; idx < 1024; idx += 256) {
        int j = idx >> 4; int c8 = (idx & 15) * 8;
        *(short8*)&sB[j][c8] = *(const short8*)&proj_wt[(long)j * 128 + c8];
    }
    __syncthreads();

    float res[32];     // res[jc*16+k] = channel jc*64 + cg*16 + k
    float s = 0.f, s2 = 0.f;
    const f32x4 zero4 = {0.f, 0.f, 0.f, 0.f};
    for (int jc = 0; jc < 2; ++jc) {
        if (jc == 1) {
            __syncthreads();   // readers of sB/sCf chunk-0 done
            for (int idx = tid; idx < 1024; idx += 256) {
                int j = idx >> 4; int c8 = (idx & 15) * 8;
                *(short8*)&sB[j][c8] = *(const short8*)&proj_wt[(long)(64 + j) * 128 + c8];
            }
            __syncthreads();
        }
        f32x4 acc[4];
        #pragma unroll
        for (int nt = 0; nt < 4; ++nt) acc[nt] = zero4;
        #pragma unroll
        for (int kk = 0; kk < 4; ++kk) {
            short8 af = *(const short8*)&sA[w16 + l16][kk * 32 + quad * 8];
            #pragma unroll
            for (int nt = 0; nt < 4; ++nt) {
                short8 bfq = *(const short8*)&sB[nt * 16 + l16][kk * 32 + quad * 8];
                acc[nt] = __builtin_amdgcn_mfma_f32_16x16x32_bf16(af, bfq, acc[nt], 0, 0, 0);
            }
        }
        #pragma unroll
        for (int nt = 0; nt < 4; ++nt) {
            int n = nt * 16 + l16;
            float bias = proj_b[jc * 64 + n];
            #pragma unroll
            for (int r = 0; r < 4; ++r) sCf[w16 + quad * 4 + r][n] = acc[nt][r] + bias;
        }
        __syncthreads();
        #pragma unroll
        for (int k = 0; k < 16; ++k) {       // residual: proj + x, keep in regs
            int cl = cg * 16 + k;
            int c = jc * 64 + cl;
            float v = sCf[tok][cl] + x[(long)(b * 128 + c) * 50176 + thw0 + tok];
            res[jc * 16 + k] = v; s += v; s2 += v * v;
        }
    }
    __syncthreads();           // sB readers done (GEMM barrier) -> stats region safe
    sPa[cg * 64 + tok] = s; sPb[cg * 64 + tok] = s2;
    __syncthreads();
    if (tid < 64) {
        float ss  = sPa[tid] + sPa[64 + tid] + sPa[128 + tid] + sPa[192 + tid];
        float ss2 = sPb[tid] + sPb[64 + tid] + sPb[128 + tid] + sPb[192 + tid];
        float mu = ss * (1.0f / 128.0f);
        float var = ss2 * (1.0f / 128.0f) - mu * mu;
        sMu[tid] = mu;
        sRstd[tid] = rsqrtf(fmaxf(var, 0.f) + 1e-5f);
    }
    __syncthreads();
    {
        float mu = sMu[tok], rstd = sRstd[tok];
        #pragma unroll
        for (int jc = 0; jc < 2; ++jc) {
            #pragma unroll
            for (int k8 = 0; k8 < 2; ++k8) {
                short8 pk;
                #pragma unroll
                for (int k = 0; k < 8; ++k) {
                    int c = jc * 64 + cg * 16 + k8 * 8 + k;
                    bf16 hv = f2b((res[jc * 16 + k8 * 8 + k] - mu) * rstd * ln_g[c] + ln_b[c]);
                    pk[k] = *(short*)&hv;
                }
                *(short8*)&lnT[tok][jc * 64 + cg * 16 + k8 * 8] = pk;
            }
        }
    }
    __syncthreads();
    // A-fragments for this wave's 16 tokens into registers
    short8 afr[4];
    #pragma unroll
    for (int kk = 0; kk < 4; ++kk)
        afr[kk] = *(const short8*)&lnT[w16 + l16][kk * 32 + quad * 8];
    __syncthreads();   // lnT reads done -> W region (sB + sCf head) reusable

    int j0i = tid >> 4, c8a = (tid & 15) * 8;   // W1 staging rows
    int ca  = tid >> 2, j8a = (tid & 3) * 8;    // W2 staging rows
    short8 r1a, r1b, r2a, r2b;
    r1a = *(const short8*)&w1t[(long)j0i * 128 + c8a];
    r1b = *(const short8*)&w1t[(long)(j0i + 16) * 128 + c8a];
    r2a = *(const short8*)&w2t[(long)ca * 512 + j8a];
    r2b = *(const short8*)&w2t[(long)(ca + 64) * 512 + j8a];
    *(short8*)&sW1[j0i][c8a]      = r1a;
    *(short8*)&sW1[j0i + 16][c8a] = r1b;
    *(short8*)&sW2[ca][j8a]       = r2a;
    *(short8*)&sW2[ca + 64][j8a]  = r2b;
    __syncthreads();

    f32x4 facc[8];
    #pragma unroll
    for (int t = 0; t < 8; ++t) facc[t] = (f32x4){0.f, 0.f, 0.f, 0.f};

    for (int ch = 0; ch < 16; ++ch) {
        if (ch < 15) {   // issue next chunk's loads; latency hides under fc1/fc2
            r1a = *(const short8*)&w1t[(long)((ch + 1) * 32 + j0i) * 128 + c8a];
            r1b = *(const short8*)&w1t[(long)((ch + 1) * 32 + j0i + 16) * 128 + c8a];
            r2a = *(const short8*)&w2t[(long)ca * 512 + (ch + 1) * 32 + j8a];
            r2b = *(const short8*)&w2t[(long)(ca + 64) * 512 + (ch + 1) * 32 + j8a];
        }
        #pragma unroll
        for (int t = 0; t < 2; ++t) {
            f32x4 a = (f32x4){0.f, 0.f, 0.f, 0.f};
            #pragma unroll
            for (int kk = 0; kk < 4; ++kk) {
                short8 bfq = *(const short8*)&sW1[t * 16 + l16][kk * 32 + quad * 8];
                a = __builtin_amdgcn_mfma_f32_16x16x32_bf16(afr[kk], bfq, a, 0, 0, 0);
            }
            float bias = b1[ch * 32 + t * 16 + l16];
            #pragma unroll
            for (int r = 0; r < 4; ++r) {
                sH[w16 + quad * 4 + r][t * 16 + l16] = f2b(gelu_f(a[r] + bias));
            }
        }
        // fc1 writes / fc2 reads of sH touch only rows [w16,w16+16): same-wave, lgkm-ordered
        bhalf4 h0 = *(const bhalf4*)&sH[w16 + l16][quad * 8];
        bhalf4 h1 = *(const bhalf4*)&sH[w16 + l16][quad * 8 + 4];
        short8 hf = {h0[0], h0[1], h0[2], h0[3], h1[0], h1[1], h1[2], h1[3]};
        #pragma unroll
        for (int t = 0; t < 8; ++t) {
            short8 wf = *(const short8*)&sW2[t * 16 + l16][quad * 8];
            facc[t] = __builtin_amdgcn_mfma_f32_16x16x32_bf16(hf, wf, facc[t], 0, 0, 0);
        }
        if (ch < 15) {
            __syncthreads();               // all readers done with current weights
            *(short8*)&sW1[j0i][c8a]      = r1a;
            *(short8*)&sW1[j0i + 16][c8a] = r1b;
            *(short8*)&sW2[ca][j8a]       = r2a;
            *(short8*)&sW2[ca + 64][j8a]  = r2b;
            __syncthreads();               // new weights visible
        }
    }
    __syncthreads();   // last fc2 reads done -> region becomes sOut
    bf16 (*sOut)[136] = lnT;
    #pragma unroll
    for (int t = 0; t < 8; ++t) {
        int c = t * 16 + l16;
        float b2v = b2[c];
        #pragma unroll
        for (int r = 0; r < 4; ++r) {
            sOut[w16 + quad * 4 + r][c] = f2b(facc[t][r] + b2v);
        }
    }
    __syncthreads();
    #pragma unroll
    for (int jc = 0; jc < 2; ++jc) {
        #pragma unroll
        for (int k8 = 0; k8 < 2; ++k8) {
            short8 ov = *(const short8*)&sOut[tok][jc * 64 + cg * 16 + k8 * 8];
            #pragma unroll
            for (int k = 0; k < 8; ++k) {
                short sv = ov[k];
                bf16 bv = *(bf16*)&sv;
                int c = jc * 64 + cg * 16 + k8 * 8 + k;
                y[(long)(b * 128 + c) * 50176 + thw0 + tok] = res[jc * 16 + k8 * 8 + k] + b2f(bv);
            }
        }
    }
}

// ----------------------------------------------------------------
extern "C" void kernel_launch(void* const* d_in, const int* in_sizes, int n_in,
                              void* d_out, int out_size, void* d_ws, size_t ws_size,
                              hipStream_t stream) {
    const float* x      = (const float*)d_in[0];
    const float* bn_g   = (const float*)d_in[1];
    const float* bn_b   = (const float*)d_in[2];
    const float* bn_m   = (const float*)d_in[3];
    const float* bn_v   = (const float*)d_in[4];
    const float* qkv_w  = (const float*)d_in[5];
    const float* qkv_b  = (const float*)d_in[6];
    const float* proj_w = (const float*)d_in[7];
    const float* proj_b = (const float*)d_in[8];
    const float* ln_g   = (const float*)d_in[9];
    const float* ln_b   = (const float*)d_in[10];
    const float* fc1_w  = (const float*)d_in[11];
    const float* fc1_b  = (const float*)d_in[12];
    const float* fc2_w  = (const float*)d_in[13];
    const float* fc2_b  = (const float*)d_in[14];
    float* out = (float*)d_out;

    // weight prep region at front of ws: qkv_wt(98304B) proj_wt(32768B) w1t(131072B) w2t(131072B)
    const size_t WB = 393216;
    char* ws = (char*)d_ws;
    bf16* qkv_wt  = (bf16*)ws;
    bf16* proj_wt = qkv_wt + 384 * 128;
    bf16* w1t     = proj_wt + 128 * 128;
    bf16* w2t     = w1t + 512 * 128;
    char* ws2 = ws + WB;

    // 4 bf16 buffers (attn + Q/K/V) per batch; NB<=16 keeps WPB>=64 so each
    // 64-token thw chunk's windows live in one batch (k45 requirement).
    int NB = 1;
    while (NB < 16 && (205520896ull / NB + WB) > ws_size) NB *= 2;
    int WPB = 1024 / NB;             // windows per batch
    int TPB = WPB * 196;             // tokens per batch
    size_t seg = (size_t)TPB * 128 * 2;  // bytes per bf16 buffer

    bf16* attn = (bf16*)(ws2);           // attn staging (k3 -> k45)
    bf16* Qb   = (bf16*)(ws2 + seg);
    bf16* Kb   = (bf16*)(ws2 + 2 * seg);
    bf16* Vb   = (bf16*)(ws2 + 3 * seg);

    k0_prep<<<dim3(192), dim3(256), 0, stream>>>(qkv_w, proj_w, fc1_w, fc2_w,
                                                 qkv_wt, proj_wt, w1t, w2t);
    for (int bi = 0; bi < NB; ++bi) {
        int bw0 = bi * WPB;
        k12_bn_qkv<<<dim3(WPB), dim3(256), 0, stream>>>(x, bn_g, bn_b, bn_m, bn_v,
                                                        qkv_wt, qkv_b, Qb, Kb, Vb, bw0);
        k3_attn<<<dim3(WPB * 4), dim3(256), 0, stream>>>(Qb, Kb, Vb, attn);
        k45_proj_mlp<<<dim3(TPB / 64), dim3(256), 0, stream>>>(attn, proj_wt, proj_b, x, out,
                                                               ln_g, ln_b, w1t, fc1_b, w2t, fc2_b, bw0);
    }
}